// Round 10
// baseline (1639.571 us; speedup 1.0000x reference)
//
#include <hip/hip_runtime.h>

// Problem constants (B=64, T=512, I=256, H=512)
#define BATCH 64
#define TSTEPS 512
#define IDIM 256
#define HDIM 512
#define MROWS (BATCH * TSTEPS)   // 32768

typedef __attribute__((address_space(1))) const void gvoid;
typedef __attribute__((address_space(3))) void lvoid;

__device__ __forceinline__ void gl2lds16(const void* g, void* l) {
    // async global->LDS, 16B per lane; LDS dest = wave-uniform base + lane*16
    __builtin_amdgcn_global_load_lds((gvoid*)g, (lvoid*)l, 16, 0, 0);
}

// ---------------------------------------------------------------------------
// K0: extract center taps: W1T[i][h] = conv1_w[h][i][1] ([k][n] layout);
//                          W2T[h][j] = conv2_w[j][h][1] ([k][n] layout)
// ---------------------------------------------------------------------------
__global__ void extract_weights(const float* __restrict__ c1w,
                                const float* __restrict__ c2w,
                                float* __restrict__ W1T,
                                float* __restrict__ W2T) {
    int tid = blockIdx.x * 256 + threadIdx.x;
    if (tid < IDIM * HDIM) {
        int i = tid >> 9;          // / 512
        int h = tid & 511;
        W1T[tid] = c1w[(h * IDIM + i) * 3 + 1];
    }
    if (tid < HDIM * HDIM) {
        int h = tid >> 9;
        int j = tid & 511;
        W2T[tid] = c2w[(j * HDIM + h) * 3 + 1];
    }
}

// ---------------------------------------------------------------------------
// fp32 GEMM, R4 shape + DOUBLE-BUFFERED LDS: C[m][n] = sum_k A[m][k]*BT[k][n]
// NUMERICS CONTRACT: one sequential k-ascending fp32 fmaf chain per output —
// bitwise identical to numpy's k-sequential sgemm microkernel (absmax 0.0 in
// rounds 1/4/5/7/8). MFMA / split-K / tree reductions flip spikes (R2/R3).
//
// R4's measured defect: staging issued then immediately barriered -> full
// global latency exposed 2x per k-iter (VALUBusy 69.6%, 191us vs 109 floor).
// Fix: dbuf. Per iter: issue gl2lds(B->nxt) + A-reg loads FIRST, compute
// 1024 FMAs from cur (~2048 cyc/wave covers the latency), scatter A-regs
// into nxt, ONE __syncthreads. The vmcnt(0) drain at the barrier lands after
// the FMA block. (Unlike m99's MFMA case, compute/iter here is long enough
// to hide staging fully.)
// 256 threads, 8x8/thread, BM=BN=128, BK=16, LDS 32KB, launch_bounds(256,2).
// ---------------------------------------------------------------------------
#define BM1 128
#define BN1 128
#define BK1 16

__global__ __launch_bounds__(256, 2) void gemm_f32(const float* __restrict__ A,
                                                   const float* __restrict__ BT,
                                                   const float* __restrict__ bias,
                                                   float* __restrict__ C,
                                                   int K, int addBias) {
    __shared__ __align__(16) float As[2][BK1 * BM1];   // [k][m]  2 x 8 KB
    __shared__ __align__(16) float Bs[2][BK1 * BN1];   // [k][n]  2 x 8 KB

    const int N = HDIM;
    int tid  = threadIdx.x;
    int lane = tid & 63;
    int wave = tid >> 6;
    int row0 = blockIdx.x * BM1;
    int col0 = blockIdx.y * BN1;
    int wm = (wave >> 1) * 64;
    int wn = (wave & 1) * 64;
    int mbase = wm + (lane >> 3) * 8;
    int nbase = wn + (lane & 7) * 8;

    float acc[8][8];
#pragma unroll
    for (int i = 0; i < 8; i++)
#pragma unroll
        for (int j = 0; j < 8; j++) acc[i][j] = 0.0f;

    // A staging: thread loads 8 floats of row (tid>>1), k-half (tid&1)*8;
    // scatters transposed into As[k][m] (2-way bank alias, free).
    int ar = tid >> 1;
    int ak = (tid & 1) * 8;
    const float* ap = A + (size_t)(row0 + ar) * K + ak;

    // B staging via gl2lds: thread covers 16B: k-row tid>>5, cols (tid&31)*4.
    const char* bp = (const char*)(BT + (size_t)(tid >> 5) * N + col0) + (tid & 31) * 16;
    const size_t bRow8 = (size_t)8 * N * sizeof(float);
    int ldsOff = tid * 16;   // byte offset within a buffer

    // ---- prologue: stage buffer 0 ----
    {
        char* bld = (char*)&Bs[0][0] + ldsOff;
        gl2lds16(bp, bld);
        gl2lds16(bp + bRow8, bld + 4096);
        bp += (size_t)BK1 * N * sizeof(float);
        float4 a0 = *(const float4*)(ap);
        float4 a1 = *(const float4*)(ap + 4);
        ap += BK1;
        float* asb = &As[0][0];
        asb[(ak + 0) * BM1 + ar] = a0.x;
        asb[(ak + 1) * BM1 + ar] = a0.y;
        asb[(ak + 2) * BM1 + ar] = a0.z;
        asb[(ak + 3) * BM1 + ar] = a0.w;
        asb[(ak + 4) * BM1 + ar] = a1.x;
        asb[(ak + 5) * BM1 + ar] = a1.y;
        asb[(ak + 6) * BM1 + ar] = a1.z;
        asb[(ak + 7) * BM1 + ar] = a1.w;
    }
    __syncthreads();

    const int nIter = K / BK1;
    for (int it = 0; it < nIter; it++) {
        int cur = it & 1;
        int nxt = cur ^ 1;
        const bool has = (it + 1 < nIter);
        float4 na0, na1;
        if (has) {
            // issue next-buffer staging FIRST (latency hidden under compute)
            char* bld = (char*)&Bs[nxt][0] + ldsOff;
            gl2lds16(bp, bld);
            gl2lds16(bp + bRow8, bld + 4096);
            bp += (size_t)BK1 * N * sizeof(float);
            na0 = *(const float4*)(ap);
            na1 = *(const float4*)(ap + 4);
            ap += BK1;
        }

        const float* asb = &As[cur][0];
        const float* bsb = &Bs[cur][0];
#pragma unroll
        for (int k = 0; k < BK1; k++) {
            float4 av0 = *(const float4*)&asb[k * BM1 + mbase];
            float4 av1 = *(const float4*)&asb[k * BM1 + mbase + 4];
            float4 bv0 = *(const float4*)&bsb[k * BN1 + nbase];
            float4 bv1 = *(const float4*)&bsb[k * BN1 + nbase + 4];
            float a8[8] = {av0.x, av0.y, av0.z, av0.w, av1.x, av1.y, av1.z, av1.w};
            float b8[8] = {bv0.x, bv0.y, bv0.z, bv0.w, bv1.x, bv1.y, bv1.z, bv1.w};
#pragma unroll
            for (int i = 0; i < 8; i++)
#pragma unroll
                for (int j = 0; j < 8; j++)
                    acc[i][j] = fmaf(a8[i], b8[j], acc[i][j]);
        }

        if (has) {
            // scatter A-regs into next buffer (after compute; waits only on
            // the A global loads issued at iter top)
            float* asn = &As[nxt][0];
            asn[(ak + 0) * BM1 + ar] = na0.x;
            asn[(ak + 1) * BM1 + ar] = na0.y;
            asn[(ak + 2) * BM1 + ar] = na0.z;
            asn[(ak + 3) * BM1 + ar] = na0.w;
            asn[(ak + 4) * BM1 + ar] = na1.x;
            asn[(ak + 5) * BM1 + ar] = na1.y;
            asn[(ak + 6) * BM1 + ar] = na1.z;
            asn[(ak + 7) * BM1 + ar] = na1.w;
        }
        __syncthreads();
    }

    float bb[8];
#pragma unroll
    for (int j = 0; j < 8; j++)
        bb[j] = addBias ? bias[col0 + nbase + j] : 0.0f;
#pragma unroll
    for (int i = 0; i < 8; i++) {
        int row = row0 + mbase + i;
        float4* cp = (float4*)&C[(size_t)row * N + col0 + nbase];
        cp[0] = (float4){acc[i][0] + bb[0], acc[i][1] + bb[1],
                         acc[i][2] + bb[2], acc[i][3] + bb[3]};
        cp[1] = (float4){acc[i][4] + bb[4], acc[i][5] + bb[5],
                         acc[i][6] + bb[6], acc[i][7] + bb[7]};
    }
}

// ---------------------------------------------------------------------------
// K2: per-(b,h) LIF scan, ping-pong register prefetch (R7 version).
// Arithmetic identical to round 1 (sequential per element).
// ---------------------------------------------------------------------------
__global__ void lif_scan1(const float* __restrict__ z1,
                          float* __restrict__ s1,
                          const float* __restrict__ th_p) {
    int gtid = blockIdx.x * blockDim.x + threadIdx.x;   // 0..32767
    int b = gtid >> 9;
    int h = gtid & 511;
    float th = *th_p;
    const float* zp = z1 + (size_t)b * TSTEPS * HDIM + h;
    float* sp = s1 + (size_t)b * TSTEPS * HDIM + h;
    float m = 0.0f;
    float bufA[16], bufB[16];
#pragma unroll
    for (int i = 0; i < 16; i++) bufA[i] = zp[(size_t)i * HDIM];
    for (int t0 = 0; t0 < TSTEPS; t0 += 32) {
#pragma unroll
        for (int i = 0; i < 16; i++) bufB[i] = zp[(size_t)(t0 + 16 + i) * HDIM];
        {
            float ss[16];
#pragma unroll
            for (int i = 0; i < 16; i++) {
                m += bufA[i];
                float thr = m / th - 1.0f;
                ss[i] = (thr >= 0.0f) ? 1.0f : 0.0f;
                if (thr > 0.0f) m -= th;
            }
#pragma unroll
            for (int i = 0; i < 16; i++) sp[(size_t)(t0 + i) * HDIM] = ss[i];
        }
        if (t0 + 32 < TSTEPS) {
#pragma unroll
            for (int i = 0; i < 16; i++) bufA[i] = zp[(size_t)(t0 + 32 + i) * HDIM];
        }
        {
            float ss[16];
#pragma unroll
            for (int i = 0; i < 16; i++) {
                m += bufB[i];
                float thr = m / th - 1.0f;
                ss[i] = (thr >= 0.0f) ? 1.0f : 0.0f;
                if (thr > 0.0f) m -= th;
            }
#pragma unroll
            for (int i = 0; i < 16; i++) sp[(size_t)(t0 + 16 + i) * HDIM] = ss[i];
        }
    }
}

// ---------------------------------------------------------------------------
// K4: per-(b,j) scan: m2 = (m2 + raw[t]) + bias, spike/reset -> out.
// Ping-pong prefetch (R7 version).
// ---------------------------------------------------------------------------
__global__ void lif_scan2(const float* __restrict__ raw,
                          const float* __restrict__ b2,
                          const float* __restrict__ th_p,
                          float* __restrict__ out) {
    int gtid = blockIdx.x * blockDim.x + threadIdx.x;   // 0..32767
    int b = gtid >> 9;
    int j = gtid & 511;
    float th = *th_p;
    float bias = b2[j];
    const float* rp = raw + (size_t)b * TSTEPS * HDIM + j;
    float* op = out + (size_t)b * TSTEPS * HDIM + j;
    float m = 0.0f;
    float bufA[16], bufB[16];
#pragma unroll
    for (int i = 0; i < 16; i++) bufA[i] = rp[(size_t)i * HDIM];
    for (int t0 = 0; t0 < TSTEPS; t0 += 32) {
#pragma unroll
        for (int i = 0; i < 16; i++) bufB[i] = rp[(size_t)(t0 + 16 + i) * HDIM];
        {
            float ss[16];
#pragma unroll
            for (int i = 0; i < 16; i++) {
                m = (m + bufA[i]) + bias;
                float thr = m / th - 1.0f;
                ss[i] = (thr >= 0.0f) ? 1.0f : 0.0f;
                if (thr > 0.0f) m -= th;
            }
#pragma unroll
            for (int i = 0; i < 16; i++) op[(size_t)(t0 + i) * HDIM] = ss[i];
        }
        if (t0 + 32 < TSTEPS) {
#pragma unroll
            for (int i = 0; i < 16; i++) bufA[i] = rp[(size_t)(t0 + 32 + i) * HDIM];
        }
        {
            float ss[16];
#pragma unroll
            for (int i = 0; i < 16; i++) {
                m = (m + bufB[i]) + bias;
                float thr = m / th - 1.0f;
                ss[i] = (thr >= 0.0f) ? 1.0f : 0.0f;
                if (thr > 0.0f) m -= th;
            }
#pragma unroll
            for (int i = 0; i < 16; i++) op[(size_t)(t0 + 16 + i) * HDIM] = ss[i];
        }
    }
}

// ---------------------------------------------------------------------------
extern "C" void kernel_launch(void* const* d_in, const int* in_sizes, int n_in,
                              void* d_out, int out_size, void* d_ws, size_t ws_size,
                              hipStream_t stream) {
    const float* x    = (const float*)d_in[0];   // (64, 512, 256)
    const float* c1w  = (const float*)d_in[1];   // (512, 256, 3)
    const float* c1b  = (const float*)d_in[2];   // (512,)
    const float* c2w  = (const float*)d_in[3];   // (512, 512, 3)
    const float* c2b  = (const float*)d_in[4];   // (512,)
    const float* th1  = (const float*)d_in[5];   // scalar
    const float* th2  = (const float*)d_in[6];   // scalar
    float* out = (float*)d_out;                  // (64, 512, 512)

    // Workspace layout (floats):
    //   W1T : 131072   (512 KB)   [k=i][n=h]
    //   W2T : 262144   (1 MB)     [k=h][n=j]
    //   bufA: 16777216 (64 MB)    z1, later m2raw   [m][n]
    //   bufS: 16777216 (64 MB)    s1                [m][h]
    float* W1T  = (float*)d_ws;
    float* W2T  = W1T + IDIM * HDIM;
    float* bufA = W2T + HDIM * HDIM;
    float* bufS = bufA + (size_t)MROWS * HDIM;

    // K0: weight extraction
    extract_weights<<<(HDIM * HDIM + 255) / 256, 256, 0, stream>>>(c1w, c2w, W1T, W2T);

    // K1: z1 = x @ W1T + b1   (M=32768, K=256, N=512) -> bufA
    {
        dim3 grid(MROWS / BM1, HDIM / BN1);
        gemm_f32<<<grid, 256, 0, stream>>>(x, W1T, c1b, bufA, IDIM, 1);
    }

    // K2: s1 scan -> bufS
    lif_scan1<<<MROWS / 64, 64, 0, stream>>>(bufA, bufS, th1);

    // K3: m2raw = s1 @ W2T   (M=32768, K=512, N=512) -> bufA
    {
        dim3 grid(MROWS / BM1, HDIM / BN1);
        gemm_f32<<<grid, 256, 0, stream>>>(bufS, W2T, (const float*)nullptr, bufA, HDIM, 0);
    }

    // K4: s2 scan -> out
    lif_scan2<<<MROWS / 64, 64, 0, stream>>>(bufA, c2b, th2, out);
}

// Round 11
// 428.722 us; speedup vs baseline: 3.8243x; 3.8243x over previous
//
#include <hip/hip_runtime.h>

// Problem constants (B=64, T=512, I=256, H=512)
#define BATCH 64
#define TSTEPS 512
#define IDIM 256
#define HDIM 512
#define MROWS (BATCH * TSTEPS)   // 32768

typedef __attribute__((address_space(1))) const void gvoid;
typedef __attribute__((address_space(3))) void lvoid;

__device__ __forceinline__ void gl2lds16(const void* g, void* l) {
    // async global->LDS, 16B per lane; LDS dest = wave-uniform base + lane*16
    __builtin_amdgcn_global_load_lds((gvoid*)g, (lvoid*)l, 16, 0, 0);
}

// ---------------------------------------------------------------------------
// K0: extract center taps: W1T[i][h] = conv1_w[h][i][1] ([k][n] layout);
//                          W2T[h][j] = conv2_w[j][h][1] ([k][n] layout)
// ---------------------------------------------------------------------------
__global__ void extract_weights(const float* __restrict__ c1w,
                                const float* __restrict__ c2w,
                                float* __restrict__ W1T,
                                float* __restrict__ W2T) {
    int tid = blockIdx.x * 256 + threadIdx.x;
    if (tid < IDIM * HDIM) {
        int i = tid >> 9;          // / 512
        int h = tid & 511;
        W1T[tid] = c1w[(h * IDIM + i) * 3 + 1];
    }
    if (tid < HDIM * HDIM) {
        int h = tid >> 9;
        int j = tid & 511;
        W2T[tid] = c2w[(j * HDIM + h) * 3 + 1];
    }
}

// ---------------------------------------------------------------------------
// fp32 GEMM — ROUND-4 SHAPE VERBATIM (best measured: G2=191us, VGPR 52, no
// spill). C[m][n] = (sum_k A[m][k]*BT[k][n]) [+ bias[n]]
// NUMERICS CONTRACT: each output is ONE sequential fmaf chain, k ascending,
// fp32 — bitwise identical to numpy's k-sequential sgemm (absmax 0.0 in
// rounds 1/4/5/7/8). MFMA / split-K / tree reductions flip spikes (R2/R3).
//
// Structure ledger (7 attempts): 8x8@256thr 2-barrier = 191us (this one);
// 16x8 variants 200-207 (latency/barrier exposure); reg-only 306 (SMEM
// lgkmcnt mixing); dbuf 1019 (scratch spill at 128-VGPR bound). This shape
// runs 16% above its LDS-pipe floor (164us) — the flat local optimum.
// ---------------------------------------------------------------------------
#define BM 128
#define BN 128
#define BK 16

__global__ __launch_bounds__(256, 2) void gemm_f32(const float* __restrict__ A,
                                                   const float* __restrict__ BT,
                                                   const float* __restrict__ bias,
                                                   float* __restrict__ C,
                                                   int K, int addBias) {
    __shared__ __align__(16) float As[BK * BM];   // [k][m]  8 KB
    __shared__ __align__(16) float Bs[BK * BN];   // [k][n]  8 KB

    const int N = HDIM;
    int tid  = threadIdx.x;
    int lane = tid & 63;
    int wave = tid >> 6;
    int row0 = blockIdx.x * BM;
    int col0 = blockIdx.y * BN;
    int wm = (wave >> 1) * 64;
    int wn = (wave & 1) * 64;
    int mbase = wm + (lane >> 3) * 8;
    int nbase = wn + (lane & 7) * 8;

    float acc[8][8];
#pragma unroll
    for (int i = 0; i < 8; i++)
#pragma unroll
        for (int j = 0; j < 8; j++) acc[i][j] = 0.0f;

    // A staging: thread loads 8 floats of row (tid>>1), k-half (tid&1)*8,
    // scatters transposed into As[k][m] (2-way bank alias, free).
    int ar = tid >> 1;
    int ak = (tid & 1) * 8;
    const float* ap = A + (size_t)(row0 + ar) * K + ak;

    // B staging via gl2lds: thread covers 16B: k-row tid>>5, cols (tid&31)*4.
    const char* bp = (const char*)(BT + (size_t)(tid >> 5) * N + col0) + (tid & 31) * 16;
    char* bld = (char*)Bs + tid * 16;
    const size_t bRow8 = (size_t)8 * N * sizeof(float);

    for (int k0 = 0; k0 < K; k0 += BK) {
        gl2lds16(bp, bld);
        gl2lds16(bp + bRow8, bld + 4096);
        float4 a0 = *(const float4*)(ap);
        float4 a1 = *(const float4*)(ap + 4);
        ap += BK;
        bp += (size_t)BK * N * sizeof(float);
        As[(ak + 0) * BM + ar] = a0.x;
        As[(ak + 1) * BM + ar] = a0.y;
        As[(ak + 2) * BM + ar] = a0.z;
        As[(ak + 3) * BM + ar] = a0.w;
        As[(ak + 4) * BM + ar] = a1.x;
        As[(ak + 5) * BM + ar] = a1.y;
        As[(ak + 6) * BM + ar] = a1.z;
        As[(ak + 7) * BM + ar] = a1.w;
        __syncthreads();

#pragma unroll
        for (int k = 0; k < BK; k++) {
            float4 av0 = *(const float4*)&As[k * BM + mbase];
            float4 av1 = *(const float4*)&As[k * BM + mbase + 4];
            float4 bv0 = *(const float4*)&Bs[k * BN + nbase];
            float4 bv1 = *(const float4*)&Bs[k * BN + nbase + 4];
            float a8[8] = {av0.x, av0.y, av0.z, av0.w, av1.x, av1.y, av1.z, av1.w};
            float b8[8] = {bv0.x, bv0.y, bv0.z, bv0.w, bv1.x, bv1.y, bv1.z, bv1.w};
#pragma unroll
            for (int i = 0; i < 8; i++)
#pragma unroll
                for (int j = 0; j < 8; j++)
                    acc[i][j] = fmaf(a8[i], b8[j], acc[i][j]);
        }
        __syncthreads();
    }

    float bb[8];
#pragma unroll
    for (int j = 0; j < 8; j++)
        bb[j] = addBias ? bias[col0 + nbase + j] : 0.0f;
#pragma unroll
    for (int i = 0; i < 8; i++) {
        int row = row0 + mbase + i;
        float4* cp = (float4*)&C[(size_t)row * N + col0 + nbase];
        cp[0] = (float4){acc[i][0] + bb[0], acc[i][1] + bb[1],
                         acc[i][2] + bb[2], acc[i][3] + bb[3]};
        cp[1] = (float4){acc[i][4] + bb[4], acc[i][5] + bb[5],
                         acc[i][6] + bb[6], acc[i][7] + bb[7]};
    }
}

// ---------------------------------------------------------------------------
// K2: per-(b,h) LIF scan, ping-pong register prefetch (R7 version, measured
// win). Arithmetic identical to round 1 (sequential per element).
// ---------------------------------------------------------------------------
__global__ void lif_scan1(const float* __restrict__ z1,
                          float* __restrict__ s1,
                          const float* __restrict__ th_p) {
    int gtid = blockIdx.x * blockDim.x + threadIdx.x;   // 0..32767
    int b = gtid >> 9;
    int h = gtid & 511;
    float th = *th_p;
    const float* zp = z1 + (size_t)b * TSTEPS * HDIM + h;
    float* sp = s1 + (size_t)b * TSTEPS * HDIM + h;
    float m = 0.0f;
    float bufA[16], bufB[16];
#pragma unroll
    for (int i = 0; i < 16; i++) bufA[i] = zp[(size_t)i * HDIM];
    for (int t0 = 0; t0 < TSTEPS; t0 += 32) {
#pragma unroll
        for (int i = 0; i < 16; i++) bufB[i] = zp[(size_t)(t0 + 16 + i) * HDIM];
        {
            float ss[16];
#pragma unroll
            for (int i = 0; i < 16; i++) {
                m += bufA[i];
                float thr = m / th - 1.0f;
                ss[i] = (thr >= 0.0f) ? 1.0f : 0.0f;
                if (thr > 0.0f) m -= th;
            }
#pragma unroll
            for (int i = 0; i < 16; i++) sp[(size_t)(t0 + i) * HDIM] = ss[i];
        }
        if (t0 + 32 < TSTEPS) {
#pragma unroll
            for (int i = 0; i < 16; i++) bufA[i] = zp[(size_t)(t0 + 32 + i) * HDIM];
        }
        {
            float ss[16];
#pragma unroll
            for (int i = 0; i < 16; i++) {
                m += bufB[i];
                float thr = m / th - 1.0f;
                ss[i] = (thr >= 0.0f) ? 1.0f : 0.0f;
                if (thr > 0.0f) m -= th;
            }
#pragma unroll
            for (int i = 0; i < 16; i++) sp[(size_t)(t0 + 16 + i) * HDIM] = ss[i];
        }
    }
}

// ---------------------------------------------------------------------------
// K4: per-(b,j) scan: m2 = (m2 + raw[t]) + bias, spike/reset -> out.
// Ping-pong prefetch (R7 version).
// ---------------------------------------------------------------------------
__global__ void lif_scan2(const float* __restrict__ raw,
                          const float* __restrict__ b2,
                          const float* __restrict__ th_p,
                          float* __restrict__ out) {
    int gtid = blockIdx.x * blockDim.x + threadIdx.x;   // 0..32767
    int b = gtid >> 9;
    int j = gtid & 511;
    float th = *th_p;
    float bias = b2[j];
    const float* rp = raw + (size_t)b * TSTEPS * HDIM + j;
    float* op = out + (size_t)b * TSTEPS * HDIM + j;
    float m = 0.0f;
    float bufA[16], bufB[16];
#pragma unroll
    for (int i = 0; i < 16; i++) bufA[i] = rp[(size_t)i * HDIM];
    for (int t0 = 0; t0 < TSTEPS; t0 += 32) {
#pragma unroll
        for (int i = 0; i < 16; i++) bufB[i] = rp[(size_t)(t0 + 16 + i) * HDIM];
        {
            float ss[16];
#pragma unroll
            for (int i = 0; i < 16; i++) {
                m = (m + bufA[i]) + bias;
                float thr = m / th - 1.0f;
                ss[i] = (thr >= 0.0f) ? 1.0f : 0.0f;
                if (thr > 0.0f) m -= th;
            }
#pragma unroll
            for (int i = 0; i < 16; i++) op[(size_t)(t0 + i) * HDIM] = ss[i];
        }
        if (t0 + 32 < TSTEPS) {
#pragma unroll
            for (int i = 0; i < 16; i++) bufA[i] = rp[(size_t)(t0 + 32 + i) * HDIM];
        }
        {
            float ss[16];
#pragma unroll
            for (int i = 0; i < 16; i++) {
                m = (m + bufB[i]) + bias;
                float thr = m / th - 1.0f;
                ss[i] = (thr >= 0.0f) ? 1.0f : 0.0f;
                if (thr > 0.0f) m -= th;
            }
#pragma unroll
            for (int i = 0; i < 16; i++) op[(size_t)(t0 + 16 + i) * HDIM] = ss[i];
        }
    }
}

// ---------------------------------------------------------------------------
extern "C" void kernel_launch(void* const* d_in, const int* in_sizes, int n_in,
                              void* d_out, int out_size, void* d_ws, size_t ws_size,
                              hipStream_t stream) {
    const float* x    = (const float*)d_in[0];   // (64, 512, 256)
    const float* c1w  = (const float*)d_in[1];   // (512, 256, 3)
    const float* c1b  = (const float*)d_in[2];   // (512,)
    const float* c2w  = (const float*)d_in[3];   // (512, 512, 3)
    const float* c2b  = (const float*)d_in[4];   // (512,)
    const float* th1  = (const float*)d_in[5];   // scalar
    const float* th2  = (const float*)d_in[6];   // scalar
    float* out = (float*)d_out;                  // (64, 512, 512)

    // Workspace layout (floats):
    //   W1T : 131072   (512 KB)   [k=i][n=h]
    //   W2T : 262144   (1 MB)     [k=h][n=j]
    //   bufA: 16777216 (64 MB)    z1, later m2raw   [m][n]
    //   bufS: 16777216 (64 MB)    s1                [m][h]
    float* W1T  = (float*)d_ws;
    float* W2T  = W1T + IDIM * HDIM;
    float* bufA = W2T + HDIM * HDIM;
    float* bufS = bufA + (size_t)MROWS * HDIM;

    // K0: weight extraction
    extract_weights<<<(HDIM * HDIM + 255) / 256, 256, 0, stream>>>(c1w, c2w, W1T, W2T);

    // K1: z1 = x @ W1T + b1   (M=32768, K=256, N=512) -> bufA
    {
        dim3 grid(MROWS / BM, HDIM / BN);
        gemm_f32<<<grid, 256, 0, stream>>>(x, W1T, c1b, bufA, IDIM, 1);
    }

    // K2: s1 scan -> bufS
    lif_scan1<<<MROWS / 64, 64, 0, stream>>>(bufA, bufS, th1);

    // K3: m2raw = s1 @ W2T   (M=32768, K=512, N=512) -> bufA
    {
        dim3 grid(MROWS / BM, HDIM / BN);
        gemm_f32<<<grid, 256, 0, stream>>>(bufS, W2T, (const float*)nullptr, bufA, HDIM, 0);
    }

    // K4: s2 scan -> out
    lif_scan2<<<MROWS / 64, 64, 0, stream>>>(bufA, c2b, th2, out);
}